// Round 15
// baseline (115.530 us; speedup 1.0000x reference)
//
#include <hip/hip_runtime.h>

#define B_   4
#define N_   4096
#define NH_  16
#define F_   8
#define D_   256
#define FF_  1024
#define H_   8
#define PE_  32
#define NG_  8192
#define NI_  65536
#define NQ_  1024

typedef short short8 __attribute__((ext_vector_type(8)));
typedef float f32x4 __attribute__((ext_vector_type(4)));

union U8 { short8 s8; uint4 u4; };

__device__ __forceinline__ float silu_f(float v) {
  return v * __builtin_amdgcn_rcpf(1.f + __expf(-v));
}
__device__ __forceinline__ unsigned short f2bf(float f) {
  unsigned int x = __float_as_uint(f);
  unsigned int r = (x + 0x7fffu + ((x >> 16) & 1u)) >> 16;
  return (unsigned short)r;
}
__device__ __forceinline__ unsigned int cvt_pk(float a, float b) {
  unsigned int r;
  asm("v_cvt_pk_bf16_f32 %0, %1, %2" : "=v"(r) : "v"(a), "v"(b));
  return r;
}
__device__ __forceinline__ unsigned short f2bf1(float v) {
  return (unsigned short)cvt_pk(v, v);
}
__device__ __forceinline__ float bf2f(unsigned short h) {
  return __uint_as_float(((unsigned int)h) << 16);
}

__device__ __forceinline__ int detect_layout(const unsigned int* w) {
  unsigned b1 = 0, b0 = 0;
#pragma unroll
  for (int i = 0; i < 64; ++i) {
    unsigned v = w[i];
    b1 |= v & 0x0000FF00u;
    b0 |= v & 0x000000FFu;
  }
  return b1 ? 0 : (b0 ? 1 : 2);
}
__device__ __forceinline__ int read_bool(const void* p, int i, int lay) {
  if (lay == 0) return ((const unsigned char*)p)[i] != 0;
  if (lay == 1) return ((const int*)p)[i] != 0;
  return ((const float*)p)[i] != 0.0f;
}

// ---------------------------------------------------------------------------
// Workspace layout.
// ---------------------------------------------------------------------------
#define WOP_OFF 0
#define W1P_OFF 65536
#define W2P_OFF (65536 + 262144)
#define WVP_OFF (65536 + 262144 + 262144)
#define WIP_OFF (65536 + 262144 + 262144 + 65536)
#define WBP_OFF (WIP_OFF + 8192)
#define WS_BASE_B ((WBP_OFF + 512) * 2)
#define DRP8_B  WS_BASE_B
#define INR8_B  (WS_BASE_B + 16384)
#define WS_MASKS_END (INR8_B + 131072)
#define ROWS_B  WS_MASKS_END
#define WS_ROWS_END (ROWS_B + 16384 * 256 * 2)
#define WS_TAIL ((65536 + 262144 + 262144) * 2)

__global__ __launch_bounds__(256) void k_pack(
    const float* __restrict__ Wo, const float* __restrict__ W1,
    const float* __restrict__ W2, const float* __restrict__ Wv,
    const float* __restrict__ Wi, const float* __restrict__ Wb,
    const void* __restrict__ drop, const void* __restrict__ inr,
    short* __restrict__ ws)
{
  int t = blockIdx.x * 256 + threadIdx.x;
  if (t < 8192) {
    int g = t & 3, n = (t >> 2) & 255, kk = t >> 10;
    int k0 = kk * 32 + g * 8;
    short8 v;
#pragma unroll
    for (int j = 0; j < 8; ++j) v[j] = (short)f2bf(Wo[(k0 + j) * 256 + n]);
    *(short8*)(ws + WOP_OFF + t * 8) = v;
  } else if (t < 40960) {
    int u = t - 8192;
    int g = u & 3, n = (u >> 2) & 1023, kk = u >> 12;
    int k0 = kk * 32 + g * 8;
    short8 v;
#pragma unroll
    for (int j = 0; j < 8; ++j) v[j] = (short)f2bf(W1[(k0 + j) * 1024 + n]);
    *(short8*)(ws + W1P_OFF + u * 8) = v;
  } else if (t < 73728) {
    int u = t - 40960;
    int g = u & 3, n = (u >> 2) & 255, kk = u >> 10;
    int k0 = kk * 32 + g * 8;
    short8 v;
#pragma unroll
    for (int j = 0; j < 8; ++j) v[j] = (short)f2bf(W2[(k0 + j) * 256 + n]);
    *(short8*)(ws + W2P_OFF + u * 8) = v;
  } else if (t < 81920) {
    int u = t - 73728;
    int g = u & 3, n = (u >> 2) & 255, kk = u >> 10;
    int k0 = kk * 32 + g * 8;
    short8 v;
#pragma unroll
    for (int j = 0; j < 8; ++j) v[j] = (short)f2bf(Wv[(k0 + j) * 256 + n]);
    *(short8*)(ws + WVP_OFF + u * 8) = v;
  } else if (t < 82944) {
    int u = t - 81920;
    int g = u & 3, n = u >> 2;
    short8 v;
#pragma unroll
    for (int j = 0; j < 8; ++j) {
      int k = g * 8 + j;
      v[j] = (k < 8) ? (short)f2bf(Wi[k * 256 + n]) : (short)0;
    }
    *(short8*)(ws + WIP_OFF + (n * 4 + g) * 8) = v;
  } else if (t < 83008) {
    int u = t - 82944;
    int g = u & 3, col = u >> 2;
    short8 v;
#pragma unroll
    for (int j = 0; j < 8; ++j) {
      int p = g * 8 + j;
      v[j] = (col < 8) ? (short)f2bf(Wb[p * 8 + col]) : (short)0;
    }
    *(short8*)(ws + WBP_OFF + (col * 4 + g) * 8) = v;
  } else if (t >= 83200) {
    int lay = detect_layout((const unsigned int*)inr);
    int t2 = t - 83200;
    char* wsb = (char*)ws;
    if (t2 < B_ * N_) {
      ((unsigned char*)(wsb + DRP8_B))[t2] =
          (unsigned char)read_bool(drop, t2, lay);
    } else if (t2 < B_ * N_ + NG_ * NH_) {
      int u = t2 - B_ * N_;
      ((unsigned char*)(wsb + INR8_B))[u] =
          (unsigned char)read_bool(inr, u, lay);
    }
  }
}

// ---------------------------------------------------------------------------
// MFMA attention v7b: split-K xs halves, NO min-wave launch bound (single-
// variable retry of R12: only the launch_bounds differs). LDS 23328 B.
// ---------------------------------------------------------------------------
#define OXS   0        // xs_half 16384; later y_bf [32][256] bf16 swz
#define OATT  16384    // att_bf [32][64] bf16 swz 4096; later outl [4][256] f32
#define ODIST 20480
#define OANG  21504
#define OKLON 22528
#define OKLAT 22784
#define OKMSK 23040
#define OGLON 23296
#define OGLAT 23312    // end 23328

__global__ __launch_bounds__(256) void k_attn_mfma(
    const float* __restrict__ x, const int* __restrict__ gli,
    const unsigned char* __restrict__ drp8, const unsigned char* __restrict__ inr8,
    const int* __restrict__ imap, const float* __restrict__ icoord,
    const float* __restrict__ gcoord, const float* __restrict__ W_pe,
    const float* __restrict__ b_in, const short* __restrict__ WiP,
    const short* __restrict__ WbP, const short* __restrict__ WvP,
    unsigned short* __restrict__ rows, float* __restrict__ out, int userows)
{
  __shared__ __align__(16) char sm[23328];
  float* distl = (float*)(sm + ODIST);
  float* angl = (float*)(sm + OANG);
  float* klon = (float*)(sm + OKLON);
  float* klat = (float*)(sm + OKLAT);
  int* kmask = (int*)(sm + OKMSK);
  float* glon = (float*)(sm + OGLON);
  float* glat = (float*)(sm + OGLAT);

  const int grp = blockIdx.x;
  const int b = grp >> 10;
  const int q = grp & (NQ_ - 1);
  const int tid = threadIdx.x;
  const int w = tid >> 6;
  const int l15 = tid & 15;
  const int g = (tid & 63) >> 4;
  const int swz = (l15 & 7) << 4;

  // P0: metadata (tid<64) + MLP half 0
  if (tid < 64) {
    int s = tid >> 4;
    int gg = gli[b * N_ + q * 4 + s];
    if ((tid & 15) == 0) {
      glon[s] = gcoord[gg];
      glat[s] = gcoord[NG_ + gg];
    }
    int id = imap[gg * NH_ + (tid & 15)];
    klon[tid] = icoord[id];
    klat[tid] = icoord[NI_ + id];
    kmask[tid] = (inr8[gg * NH_ + (tid & 15)] == 0) |
                 (drp8[b * N_ + q * 4 + s] != 0);
  }

  // xs_half store slot: k0 = (w&1)*16 + g*4; byte = d*64 + sl
  const int sl = (((((w & 1) * 2 + (g >> 1)) ^ ((l15 >> 1) & 3)) << 4) | ((g & 1) * 8));
  const int nb = (w >> 1) * 8;
  const float4* xp = (const float4*)(x + (size_t)(b * N_ + q * 4) * 128);

  // ---- MLP half 0 (tokens 0..31) ----
  {
    short8 a = {0, 0, 0, 0, 0, 0, 0, 0};
    if (g == 0) {
      int tok = (w & 1) * 16 + l15;
      float4 xa = xp[tok * 2];
      float4 xc = xp[tok * 2 + 1];
      U8 u;
      u.u4.x = cvt_pk(xa.x, xa.y);
      u.u4.y = cvt_pk(xa.z, xa.w);
      u.u4.z = cvt_pk(xc.x, xc.y);
      u.u4.w = cvt_pk(xc.z, xc.w);
      a = u.s8;
    }
#pragma unroll
    for (int nf = 0; nf < 8; ++nf) {
      int d = (nb + nf) * 16 + l15;
      short8 bv = *(const short8*)(WiP + (d * 4 + g) * 8);
      f32x4 accM = {0.f, 0.f, 0.f, 0.f};
      accM = __builtin_amdgcn_mfma_f32_16x16x32_bf16(a, bv, accM, 0, 0, 0);
      float bn = b_in[d];
      uint2 pv;
      pv.x = cvt_pk(silu_f(accM[0] + bn), silu_f(accM[1] + bn));
      pv.y = cvt_pk(silu_f(accM[2] + bn), silu_f(accM[3] + bn));
      *(uint2*)(sm + OXS + d * 64 + sl) = pv;
    }
  }
  __syncthreads();   // xs_h0 + metadata ready

  // P1: dist/ang
  {
    const int t = tid >> 6, k = tid & 63;
    float dlon = klon[k] - glon[t];
    float dlat = klat[k] - glat[t];
    distl[tid] = sqrtf(dlon * dlon + dlat * dlat + 1e-12f);
    angl[tid] = atan2f(dlat, dlon);
  }
  __syncthreads();

  // P2: scores via MFMA + in-register softmax -> att_bf
  {
    float wpe0[8], wpe1[8];
    {
      const float4* wp = (const float4*)W_pe;
      float4 w0a = wp[g * 2], w0b = wp[g * 2 + 1];
      float4 w1a = wp[8 + g * 2], w1b = wp[8 + g * 2 + 1];
      wpe0[0] = w0a.x; wpe0[1] = w0a.y; wpe0[2] = w0a.z; wpe0[3] = w0a.w;
      wpe0[4] = w0b.x; wpe0[5] = w0b.y; wpe0[6] = w0b.z; wpe0[7] = w0b.w;
      wpe1[0] = w1a.x; wpe1[1] = w1a.y; wpe1[2] = w1a.z; wpe1[3] = w1a.w;
      wpe1[4] = w1b.x; wpe1[5] = w1b.y; wpe1[6] = w1b.z; wpe1[7] = w1b.w;
    }
    short8 wb = *(const short8*)(WbP + (l15 * 4 + g) * 8);
    f32x4 accS[4];
#pragma unroll
    for (int i = 0; i < 4; ++i) {
      int row = (w * 4 + i) * 16 + l15;
      float dd = distl[row];
      float aa = angl[row];
      float pe[8];
#pragma unroll
      for (int j = 0; j < 8; ++j)
        pe[j] = silu_f(fmaf(dd, wpe0[j], aa * wpe1[j]));
      U8 pu;
      pu.u4.x = cvt_pk(pe[0], pe[1]);
      pu.u4.y = cvt_pk(pe[2], pe[3]);
      pu.u4.z = cvt_pk(pe[4], pe[5]);
      pu.u4.w = cvt_pk(pe[6], pe[7]);
      f32x4 z = {0.f, 0.f, 0.f, 0.f};
      accS[i] = __builtin_amdgcn_mfma_f32_16x16x32_bf16(pu.s8, wb, z, 0, 0, 0);
    }
    float sv[16];
    float mx = -1e30f;
#pragma unroll
    for (int i = 0; i < 4; ++i)
#pragma unroll
      for (int r = 0; r < 4; ++r) {
        int k = i * 16 + g * 4 + r;
        float s = kmask[k] ? -1e9f : accS[i][r];
        sv[i * 4 + r] = s;
        mx = fmaxf(mx, s);
      }
    mx = fmaxf(mx, __shfl_xor(mx, 16));
    mx = fmaxf(mx, __shfl_xor(mx, 32));
    float sum = 0.f;
#pragma unroll
    for (int u = 0; u < 16; ++u) { sv[u] = __expf(sv[u] - mx); sum += sv[u]; }
    sum += __shfl_xor(sum, 16);
    sum += __shfl_xor(sum, 32);
    float inv = __builtin_amdgcn_rcpf(sum);
    if (l15 < 8) {
      int row = l15 * 4 + w;
      int rs = (row & 7) << 4;
#pragma unroll
      for (int i = 0; i < 4; ++i) {
        uint2 pv;
        pv.x = cvt_pk(sv[i * 4 + 0] * inv, sv[i * 4 + 1] * inv);
        pv.y = cvt_pk(sv[i * 4 + 2] * inv, sv[i * 4 + 3] * inv);
        *(uint2*)(sm + OATT + ((row * 128 + (i * 16 + g * 4) * 2) ^ rs)) = pv;
      }
    }
  }
  __syncthreads();

  // P3: y GEMM half 0 (k 0..31)
  f32x4 accY[2][4];
  {
    f32x4 z = {0.f, 0.f, 0.f, 0.f};
#pragma unroll
    for (int mi = 0; mi < 2; ++mi)
#pragma unroll
      for (int ni = 0; ni < 4; ++ni) accY[mi][ni] = z;
  }
  {
    short8 a0 = *(const short8*)(sm + OATT + ((l15 * 128 + g * 16) ^ swz));
    short8 a1 = *(const short8*)(sm + OATT + (((16 + l15) * 128 + g * 16) ^ swz));
#pragma unroll
    for (int ni = 0; ni < 4; ++ni) {
      int d = w * 64 + ni * 16 + l15;
      short8 bf = *(const short8*)(sm + OXS + d * 64 +
                                   ((g ^ ((l15 >> 1) & 3)) << 4));
      accY[0][ni] = __builtin_amdgcn_mfma_f32_16x16x32_bf16(a0, bf, accY[0][ni], 0, 0, 0);
      accY[1][ni] = __builtin_amdgcn_mfma_f32_16x16x32_bf16(a1, bf, accY[1][ni], 0, 0, 0);
    }
  }
  __syncthreads();   // xs_h0 dead

  // P4: MLP half 1 (tokens 32..63)
  {
    short8 a = {0, 0, 0, 0, 0, 0, 0, 0};
    if (g == 0) {
      int tok = 32 + (w & 1) * 16 + l15;
      float4 xa = xp[tok * 2];
      float4 xc = xp[tok * 2 + 1];
      U8 u;
      u.u4.x = cvt_pk(xa.x, xa.y);
      u.u4.y = cvt_pk(xa.z, xa.w);
      u.u4.z = cvt_pk(xc.x, xc.y);
      u.u4.w = cvt_pk(xc.z, xc.w);
      a = u.s8;
    }
#pragma unroll
    for (int nf = 0; nf < 8; ++nf) {
      int d = (nb + nf) * 16 + l15;
      short8 bv = *(const short8*)(WiP + (d * 4 + g) * 8);
      f32x4 accM = {0.f, 0.f, 0.f, 0.f};
      accM = __builtin_amdgcn_mfma_f32_16x16x32_bf16(a, bv, accM, 0, 0, 0);
      float bn = b_in[d];
      uint2 pv;
      pv.x = cvt_pk(silu_f(accM[0] + bn), silu_f(accM[1] + bn));
      pv.y = cvt_pk(silu_f(accM[2] + bn), silu_f(accM[3] + bn));
      *(uint2*)(sm + OXS + d * 64 + sl) = pv;
    }
  }
  __syncthreads();

  // P5: y GEMM half 1 (k 32..63)
  {
    short8 a0 = *(const short8*)(sm + OATT + ((l15 * 128 + 64 + g * 16) ^ swz));
    short8 a1 = *(const short8*)(sm + OATT + (((16 + l15) * 128 + 64 + g * 16) ^ swz));
#pragma unroll
    for (int ni = 0; ni < 4; ++ni) {
      int d = w * 64 + ni * 16 + l15;
      short8 bf = *(const short8*)(sm + OXS + d * 64 +
                                   ((g ^ ((l15 >> 1) & 3)) << 4));
      accY[0][ni] = __builtin_amdgcn_mfma_f32_16x16x32_bf16(a0, bf, accY[0][ni], 0, 0, 0);
      accY[1][ni] = __builtin_amdgcn_mfma_f32_16x16x32_bf16(a1, bf, accY[1][ni], 0, 0, 0);
    }
  }
  __syncthreads();   // xs_h1 dead

  // P6: y -> LDS bf16 [32][256] swizzled (OXS)
#pragma unroll
  for (int mi = 0; mi < 2; ++mi)
#pragma unroll
    for (int ni = 0; ni < 4; ++ni)
#pragma unroll
      for (int r = 0; r < 4; ++r) {
        int row = mi * 16 + g * 4 + r;
        int col = w * 64 + ni * 16 + l15;
        *(unsigned short*)(sm + OXS + ((row * 512 + col * 2) ^ ((row & 7) << 4))) =
            f2bf1(accY[mi][ni][r]);
      }
  __syncthreads();

  // P7: out[t,col] = sum_c y[h(col)*4+t][c] * Wv[c][col]
  {
    const int mf = w >> 1;
    f32x4 accV[4];
    {
      f32x4 z = {0.f, 0.f, 0.f, 0.f};
#pragma unroll
      for (int ni = 0; ni < 4; ++ni) accV[ni] = z;
    }
#pragma unroll
    for (int kk = 0; kk < 8; ++kk) {
      short8 a = *(const short8*)(sm + OXS +
          (((mf * 16 + l15) * 512 + kk * 64 + g * 16) ^ swz));
#pragma unroll
      for (int ni = 0; ni < 4; ++ni) {
        int col = w * 64 + ni * 16 + l15;
        short8 bv = *(const short8*)(WvP + ((size_t)(kk * 256 + col)) * 32 + g * 8);
        accV[ni] = __builtin_amdgcn_mfma_f32_16x16x32_bf16(a, bv, accV[ni], 0, 0, 0);
      }
    }
    float* outl = (float*)(sm + OATT);
    const int gb = (w & 1) * 2;
#pragma unroll
    for (int ni = 0; ni < 4; ++ni) {
      if (g == gb + (ni >> 1)) {
#pragma unroll
        for (int r = 0; r < 4; ++r)
          outl[r * 256 + w * 64 + ni * 16 + l15] = accV[ni][r];
      }
    }
  }
  __syncthreads();

  // P8: write out
  if (userows) {
    const float* outl = (const float*)(sm + OATT);
    unsigned* rb = (unsigned*)(rows + (size_t)grp * (4 * D_));
    int t2 = tid >> 7;
    int c2 = tid & 127;
#pragma unroll
    for (int tt = 0; tt < 2; ++tt) {
      int t = tt * 2 + t2;
      rb[t * 128 + c2] = cvt_pk(outl[t * 256 + 2 * c2],
                                outl[t * 256 + 2 * c2 + 1]);
    }
  } else {
    const float* outl = (const float*)(sm + OATT);
    float* ob = out + (size_t)grp * (4 * D_);
#pragma unroll
    for (int t = 0; t < 4; ++t) ob[t * 256 + tid] = outl[t * 256 + tid];
  }
}

// ---------------------------------------------------------------------------
// Fallback VALU attention (round-2, passing).
// ---------------------------------------------------------------------------
__global__ __launch_bounds__(256) void k_attn_valu(
    const float* __restrict__ x, const int* __restrict__ gli,
    const void* __restrict__ drop, const int* __restrict__ imap,
    const void* __restrict__ inr, const float* __restrict__ icoord,
    const float* __restrict__ gcoord, const float* __restrict__ W_in,
    const float* __restrict__ b_in, const float* __restrict__ W_pe,
    const float* __restrict__ W_bias, const float* __restrict__ W_v,
    float* __restrict__ out)
{
  __shared__ __align__(16) float xl[512];
  __shared__ float glon[4], glat[4];
  __shared__ int gidx[4], dropf[4];
  __shared__ float klon[64], klat[64];
  __shared__ int kmask[64];
  __shared__ __align__(16) unsigned short xs[64 * D_];
  __shared__ __align__(16) float att[32 * 64];
  __shared__ __align__(16) float yl[4 * 8 * 260];

  const int grp = blockIdx.x;
  const int b = grp >> 10;
  const int q = grp & (NQ_ - 1);
  const int tid = threadIdx.x;
  const int lay = detect_layout((const unsigned int*)inr);

  if (tid < 4) {
    int g = gli[b * N_ + q * 4 + tid];
    gidx[tid] = g;
    glon[tid] = gcoord[g];
    glat[tid] = gcoord[NG_ + g];
    dropf[tid] = read_bool(drop, b * N_ + q * 4 + tid, lay);
  }
  const float* xb = x + (size_t)(b * N_ + q * 4) * (NH_ * F_);
  xl[tid] = xb[tid];
  xl[tid + 256] = xb[tid + 256];
  __syncthreads();

  if (tid < 64) {
    int s = tid >> 4;
    int g = gidx[s];
    int id = imap[g * NH_ + (tid & 15)];
    klon[tid] = icoord[id];
    klat[tid] = icoord[NI_ + id];
    kmask[tid] = (read_bool(inr, g * NH_ + (tid & 15), lay) == 0) | dropf[s];
  }
  {
    float w[8];
#pragma unroll
    for (int c = 0; c < 8; ++c) w[c] = W_in[c * D_ + tid];
    float bi = b_in[tid];
#pragma unroll 4
    for (int k = 0; k < 64; ++k) {
      float v = bi;
#pragma unroll
      for (int c = 0; c < 8; ++c) v = fmaf(xl[k * 8 + c], w[c], v);
      xs[k * D_ + tid] = f2bf(silu_f(v));
    }
  }
  __syncthreads();
  {
    const int t = tid >> 6, k = tid & 63;
    float dlon = klon[k] - glon[t];
    float dlat = klat[k] - glat[t];
    float dist = sqrtf(dlon * dlon + dlat * dlat + 1e-12f);
    float ang = atan2f(dlat, dlon);
    float bias[8];
#pragma unroll
    for (int h = 0; h < 8; ++h) bias[h] = 0.f;
#pragma unroll
    for (int p = 0; p < 32; ++p) {
      float pv = silu_f(fmaf(dist, W_pe[p], ang * W_pe[32 + p]));
#pragma unroll
      for (int h = 0; h < 8; ++h) bias[h] = fmaf(pv, W_bias[p * 8 + h], bias[h]);
    }
    const bool mk = (kmask[k] != 0);
#pragma unroll
    for (int h = 0; h < 8; ++h)
      att[(h * 4 + t) * 64 + k] = mk ? -1e9f : bias[h];
  }
  __syncthreads();
  {
    const int row = tid >> 3, l8 = tid & 7;
    float sv[8];
    float mx = -1e30f;
#pragma unroll
    for (int i = 0; i < 8; ++i) { sv[i] = att[row * 64 + l8 + i * 8]; mx = fmaxf(mx, sv[i]); }
#pragma unroll
    for (int off = 1; off < 8; off <<= 1) mx = fmaxf(mx, __shfl_xor(mx, off, 8));
    float sm = 0.f;
#pragma unroll
    for (int i = 0; i < 8; ++i) { sv[i] = __expf(sv[i] - mx); sm += sv[i]; }
#pragma unroll
    for (int off = 1; off < 8; off <<= 1) sm += __shfl_xor(sm, off, 8);
    float inv = 1.f / sm;
#pragma unroll
    for (int i = 0; i < 8; ++i) att[row * 64 + l8 + i * 8] = sv[i] * inv;
  }
  __syncthreads();
  {
    float acc[32];
#pragma unroll
    for (int r = 0; r < 32; ++r) acc[r] = 0.f;
    for (int k4 = 0; k4 < 64; k4 += 4) {
      float xv0 = bf2f(xs[(k4 + 0) * D_ + tid]);
      float xv1 = bf2f(xs[(k4 + 1) * D_ + tid]);
      float xv2 = bf2f(xs[(k4 + 2) * D_ + tid]);
      float xv3 = bf2f(xs[(k4 + 3) * D_ + tid]);
#pragma unroll
      for (int r = 0; r < 32; ++r) {
        float4 a = *(const float4*)&att[r * 64 + k4];
        acc[r] = fmaf(a.x, xv0, acc[r]);
        acc[r] = fmaf(a.y, xv1, acc[r]);
        acc[r] = fmaf(a.z, xv2, acc[r]);
        acc[r] = fmaf(a.w, xv3, acc[r]);
      }
    }
#pragma unroll
    for (int r = 0; r < 32; ++r)
      yl[(r & 3) * 2080 + (r >> 2) * 260 + tid] = acc[r];
  }
  __syncthreads();
  {
    const int h = tid >> 5;
    float o0 = 0.f, o1 = 0.f, o2 = 0.f, o3 = 0.f;
    for (int c = 0; c < 256; c += 4) {
      float w0 = W_v[(c + 0) * D_ + tid];
      float w1 = W_v[(c + 1) * D_ + tid];
      float w2 = W_v[(c + 2) * D_ + tid];
      float w3 = W_v[(c + 3) * D_ + tid];
      float4 y0 = *(const float4*)&yl[0 * 2080 + h * 260 + c];
      float4 y1 = *(const float4*)&yl[1 * 2080 + h * 260 + c];
      float4 y2 = *(const float4*)&yl[2 * 2080 + h * 260 + c];
      float4 y3 = *(const float4*)&yl[3 * 2080 + h * 260 + c];
      o0 = fmaf(y0.x, w0, o0); o0 = fmaf(y0.y, w1, o0); o0 = fmaf(y0.z, w2, o0); o0 = fmaf(y0.w, w3, o0);
      o1 = fmaf(y1.x, w0, o1); o1 = fmaf(y1.y, w1, o1); o1 = fmaf(y1.z, w2, o1); o1 = fmaf(y1.w, w3, o1);
      o2 = fmaf(y2.x, w0, o2); o2 = fmaf(y2.y, w1, o2); o2 = fmaf(y2.z, w2, o2); o2 = fmaf(y2.w, w3, o2);
      o3 = fmaf(y3.x, w0, o3); o3 = fmaf(y3.y, w1, o3); o3 = fmaf(y3.z, w2, o3); o3 = fmaf(y3.w, w3, o3);
    }
    float* ob = out + (size_t)grp * (4 * D_);
    ob[0 * D_ + tid] = o0;
    ob[1 * D_ + tid] = o1;
    ob[2 * D_ + tid] = o2;
    ob[3 * D_ + tid] = o3;
  }
}

// ---------------------------------------------------------------------------
// MFMA tail: 32 rows/block, 512 blocks; bf16 or f32 source.
// ---------------------------------------------------------------------------
template<int MI>
__device__ __forceinline__ void gemm_mfma(
    f32x4 acc[MI][4], const char* As, const short* Bp,
    int N, int kk0, int colbase, int l15, int g)
{
#pragma unroll
  for (int kk = 0; kk < 8; ++kk) {
    short8 a[MI], bv[4];
#pragma unroll
    for (int mi = 0; mi < MI; ++mi) {
      int row = mi * 16 + l15;
      int byte = (row * 512 + kk * 64 + g * 16) ^ ((row & 7) << 4);
      a[mi] = *(const short8*)(As + byte);
    }
#pragma unroll
    for (int ni = 0; ni < 4; ++ni) {
      int col = colbase + ni * 16 + l15;
      size_t off = ((size_t)(kk0 + kk) * N + col) * 32 + g * 8;
      bv[ni] = *(const short8*)(Bp + off);
    }
#pragma unroll
    for (int mi = 0; mi < MI; ++mi)
#pragma unroll
      for (int ni = 0; ni < 4; ++ni)
        acc[mi][ni] = __builtin_amdgcn_mfma_f32_16x16x32_bf16(
            a[mi], bv[ni], acc[mi][ni], 0, 0, 0);
  }
}

__global__ __launch_bounds__(256) void k_tail_mfma(
    const float* __restrict__ g1v, const float* __restrict__ b1v,
    const float* __restrict__ g2v, const float* __restrict__ b2v,
    const short* __restrict__ WoP, const short* __restrict__ W1P,
    const short* __restrict__ W2P, const unsigned short* __restrict__ rowsrc,
    float* __restrict__ io, int userows)
{
  __shared__ __align__(16) unsigned short sA1[32 * 256];
  __shared__ __align__(16) unsigned short sU[32 * 256];
  __shared__ float sPs[4][32];
  __shared__ float sPss[4][32];

  const int tid = threadIdx.x;
  const int w = tid >> 6;
  const int l15 = tid & 15;
  const int g = (tid & 63) >> 4;
  float* base = io + (size_t)blockIdx.x * (32 * 256);

  if (userows) {
    const unsigned short* rb = rowsrc + (size_t)blockIdx.x * (32 * 256);
#pragma unroll
    for (int i = 0; i < 8; ++i) {
      int e = (tid + 256 * i) * 4;
      int row = e >> 8, c = e & 255;
      uint2 v = *(const uint2*)(rb + e);
      int byte = (row * 512 + c * 2) ^ ((row & 7) << 4);
      *(uint2*)((char*)sU + byte) = v;
    }
  } else {
#pragma unroll
    for (int i = 0; i < 8; ++i) {
      int e = (tid + 256 * i) * 4;
      int row = e >> 8, c = e & 255;
      float4 v = *(const float4*)(base + e);
      uint2 pv;
      pv.x = cvt_pk(v.x, v.y);
      pv.y = cvt_pk(v.z, v.w);
      int byte = (row * 512 + c * 2) ^ ((row & 7) << 4);
      *(uint2*)((char*)sU + byte) = pv;
    }
  }
  __syncthreads();

  f32x4 acc[2][4];
  {
    f32x4 z = {0.f, 0.f, 0.f, 0.f};
#pragma unroll
    for (int mi = 0; mi < 2; ++mi)
#pragma unroll
      for (int ni = 0; ni < 4; ++ni) acc[mi][ni] = z;
  }
  gemm_mfma<2>(acc, (const char*)sU, WoP, 256, 0, w * 64, l15, g);

#pragma unroll
  for (int mi = 0; mi < 2; ++mi)
#pragma unroll
    for (int r = 0; r < 4; ++r) {
      float a0 = acc[mi][0][r], a1 = acc[mi][1][r], a2 = acc[mi][2][r], a3 = acc[mi][3][r];
      float s = a0 + a1 + a2 + a3;
      float ss = a0 * a0 + a1 * a1 + a2 * a2 + a3 * a3;
#pragma unroll
      for (int off = 1; off < 16; off <<= 1) {
        s += __shfl_xor(s, off);
        ss += __shfl_xor(ss, off);
      }
      if (l15 == 0) {
        int row = 16 * mi + 4 * g + r;
        sPs[w][row] = s;
        sPss[w][row] = ss;
      }
    }
  __syncthreads();

  {
    float ga[4], bb[4];
#pragma unroll
    for (int ni = 0; ni < 4; ++ni) {
      int col = 64 * w + 16 * ni + l15;
      ga[ni] = g1v[col];
      bb[ni] = b1v[col];
    }
#pragma unroll
    for (int mi = 0; mi < 2; ++mi)
#pragma unroll
      for (int r = 0; r < 4; ++r) {
        int row = 16 * mi + 4 * g + r;
        float S = sPs[0][row] + sPs[1][row] + sPs[2][row] + sPs[3][row];
        float SS = sPss[0][row] + sPss[1][row] + sPss[2][row] + sPss[3][row];
        float mu = S * (1.f / 256.f);
        float rs = rsqrtf(SS * (1.f / 256.f) - mu * mu + 1e-5f);
#pragma unroll
        for (int ni = 0; ni < 4; ++ni) {
          int col = 64 * w + 16 * ni + l15;
          float val = (acc[mi][ni][r] - mu) * rs * ga[ni] + bb[ni];
          acc[mi][ni][r] = val;
          int byte = (row * 512 + col * 2) ^ ((row & 7) << 4);
          *(unsigned short*)((char*)sA1 + byte) = f2bf1(val);
        }
      }
  }
  __syncthreads();

  for (int p = 0; p < 4; ++p) {
    f32x4 acc2[2][4];
    {
      f32x4 z = {0.f, 0.f, 0.f, 0.f};
#pragma unroll
      for (int mi = 0; mi < 2; ++mi)
#pragma unroll
        for (int ni = 0; ni < 4; ++ni) acc2[mi][ni] = z;
    }
    gemm_mfma<2>(acc2, (const char*)sA1, W1P, 1024, 0, p * 256 + w * 64, l15, g);
#pragma unroll
    for (int mi = 0; mi < 2; ++mi)
#pragma unroll
      for (int ni = 0; ni < 4; ++ni)
#pragma unroll
        for (int r = 0; r < 4; ++r) {
          int row = 16 * mi + 4 * g + r;
          int col = 64 * w + 16 * ni + l15;
          int byte = (row * 512 + col * 2) ^ ((row & 7) << 4);
          *(unsigned short*)((char*)sU + byte) = f2bf1(silu_f(acc2[mi][ni][r]));
        }
    __syncthreads();
    gemm_mfma<2>(acc, (const char*)sU, W2P, 256, p * 8, w * 64, l15, g);
    __syncthreads();
  }

#pragma unroll
  for (int mi = 0; mi < 2; ++mi)
#pragma unroll
    for (int r = 0; r < 4; ++r) {
      float a0 = acc[mi][0][r], a1 = acc[mi][1][r], a2 = acc[mi][2][r], a3 = acc[mi][3][r];
      float s = a0 + a1 + a2 + a3;
      float ss = a0 * a0 + a1 * a1 + a2 * a2 + a3 * a3;
#pragma unroll
      for (int off = 1; off < 16; off <<= 1) {
        s += __shfl_xor(s, off);
        ss += __shfl_xor(ss, off);
      }
      if (l15 == 0) {
        int row = 16 * mi + 4 * g + r;
        sPs[w][row] = s;
        sPss[w][row] = ss;
      }
    }
  __syncthreads();

  {
    float ga[4], bb[4];
#pragma unroll
    for (int ni = 0; ni < 4; ++ni) {
      int col = 64 * w + 16 * ni + l15;
      ga[ni] = g2v[col];
      bb[ni] = b2v[col];
    }
#pragma unroll
    for (int mi = 0; mi < 2; ++mi)
#pragma unroll
      for (int r = 0; r < 4; ++r) {
        int row = 16 * mi + 4 * g + r;
        float S = sPs[0][row] + sPs[1][row] + sPs[2][row] + sPs[3][row];
        float SS = sPss[0][row] + sPss[1][row] + sPss[2][row] + sPss[3][row];
        float mu = S * (1.f / 256.f);
        float rs = rsqrtf(SS * (1.f / 256.f) - mu * mu + 1e-5f);
#pragma unroll
        for (int ni = 0; ni < 4; ++ni) {
          int col = 64 * w + 16 * ni + l15;
          base[row * 256 + col] = (acc[mi][ni][r] - mu) * rs * ga[ni] + bb[ni];
        }
      }
  }
}

// ---------------------------------------------------------------------------
// Fallback VALU tail.
// ---------------------------------------------------------------------------
__global__ __launch_bounds__(256) void k_tail(
    const float* __restrict__ Wo, const float* __restrict__ W1,
    const float* __restrict__ W2, const float* __restrict__ g1,
    const float* __restrict__ b1, const float* __restrict__ g2,
    const float* __restrict__ b2, float* __restrict__ io)
{
  __shared__ __align__(16) float rl[16 * 260];
  __shared__ __align__(16) float h1[16 * 260];
  __shared__ __align__(16) unsigned short u[16 * FF_];
  const int tid = threadIdx.x;
  float* base = io + (size_t)blockIdx.x * (16 * D_);

#pragma unroll
  for (int r = 0; r < 16; ++r) rl[r * 260 + tid] = base[r * D_ + tid];
  __syncthreads();
  {
    float acc[16];
#pragma unroll
    for (int r = 0; r < 16; ++r) acc[r] = 0.f;
    for (int c = 0; c < 256; c += 4) {
      float w0 = Wo[(c + 0) * D_ + tid], w1 = Wo[(c + 1) * D_ + tid];
      float w2 = Wo[(c + 2) * D_ + tid], w3 = Wo[(c + 3) * D_ + tid];
#pragma unroll
      for (int r = 0; r < 16; ++r) {
        float4 rv = *(const float4*)&rl[r * 260 + c];
        acc[r] = fmaf(rv.x, w0, acc[r]); acc[r] = fmaf(rv.y, w1, acc[r]);
        acc[r] = fmaf(rv.z, w2, acc[r]); acc[r] = fmaf(rv.w, w3, acc[r]);
      }
    }
#pragma unroll
    for (int r = 0; r < 16; ++r) h1[r * 260 + tid] = acc[r];
  }
  __syncthreads();
  {
    const int r = tid >> 4, l = tid & 15;
    float s = 0.f, ss = 0.f;
#pragma unroll
    for (int i = 0; i < 16; ++i) { float v = h1[r * 260 + l + i * 16]; s += v; ss += v * v; }
#pragma unroll
    for (int off = 1; off < 16; off <<= 1) { s += __shfl_xor(s, off, 16); ss += __shfl_xor(ss, off, 16); }
    float mu = s * (1.f / 256.f);
    float rs = rsqrtf(ss * (1.f / 256.f) - mu * mu + 1e-5f);
#pragma unroll
    for (int i = 0; i < 16; ++i) {
      int d = l + i * 16;
      h1[r * 260 + d] = (h1[r * 260 + d] - mu) * rs * g1[d] + b1[d];
    }
  }
  __syncthreads();
  for (int fo = 0; fo < 4; ++fo) {
    const int f = fo * 256 + tid;
    float a2[16];
#pragma unroll
    for (int r = 0; r < 16; ++r) a2[r] = 0.f;
    for (int c = 0; c < 256; c += 4) {
      float w0 = W1[(c + 0) * FF_ + f], w1 = W1[(c + 1) * FF_ + f];
      float w2 = W1[(c + 2) * FF_ + f], w3 = W1[(c + 3) * FF_ + f];
#pragma unroll
      for (int r = 0; r < 16; ++r) {
        float4 hv = *(const float4*)&h1[r * 260 + c];
        a2[r] = fmaf(hv.x, w0, a2[r]); a2[r] = fmaf(hv.y, w1, a2[r]);
        a2[r] = fmaf(hv.z, w2, a2[r]); a2[r] = fmaf(hv.w, w3, a2[r]);
      }
    }
#pragma unroll
    for (int r = 0; r < 16; ++r) u[r * FF_ + f] = f2bf(silu_f(a2[r]));
  }
  __syncthreads();
  {
    float a3[16];
#pragma unroll
    for (int r = 0; r < 16; ++r) a3[r] = h1[r * 260 + tid];
    for (int f = 0; f < FF_; f += 8) {
      float w[8];
#pragma unroll
      for (int i = 0; i < 8; ++i) w[i] = W2[(f + i) * D_ + tid];
#pragma unroll
      for (int r = 0; r < 16; ++r) {
        uint4 uv = *(const uint4*)&u[r * FF_ + f];
        a3[r] = fmaf(__uint_as_float(uv.x << 16), w[0], a3[r]);
        a3[r] = fmaf(__uint_as_float(uv.x & 0xffff0000u), w[1], a3[r]);
        a3[r] = fmaf(__uint_as_float(uv.y << 16), w[2], a3[r]);
        a3[r] = fmaf(__uint_as_float(uv.y & 0xffff0000u), w[3], a3[r]);
        a3[r] = fmaf(__uint_as_float(uv.z << 16), w[4], a3[r]);
        a3[r] = fmaf(__uint_as_float(uv.z & 0xffff0000u), w[5], a3[r]);
        a3[r] = fmaf(__uint_as_float(uv.w << 16), w[6], a3[r]);
        a3[r] = fmaf(__uint_as_float(uv.w & 0xffff0000u), w[7], a3[r]);
      }
    }
#pragma unroll
    for (int r = 0; r < 16; ++r) rl[r * 260 + tid] = a3[r];
  }
  __syncthreads();
  {
    const int r = tid >> 4, l = tid & 15;
    float s = 0.f, ss = 0.f;
#pragma unroll
    for (int i = 0; i < 16; ++i) { float v = rl[r * 260 + l + i * 16]; s += v; ss += v * v; }
#pragma unroll
    for (int off = 1; off < 16; off <<= 1) { s += __shfl_xor(s, off, 16); ss += __shfl_xor(ss, off, 16); }
    float mu = s * (1.f / 256.f);
    float rs = rsqrtf(ss * (1.f / 256.f) - mu * mu + 1e-5f);
#pragma unroll
    for (int i = 0; i < 16; ++i) {
      int d = l + i * 16;
      base[r * D_ + d] = (rl[r * 260 + d] - mu) * rs * g2[d] + b2[d];
    }
  }
}

extern "C" void kernel_launch(void* const* d_in, const int* in_sizes, int n_in,
                              void* d_out, int out_size, void* d_ws, size_t ws_size,
                              hipStream_t stream) {
  (void)in_sizes; (void)n_in; (void)out_size;
  const float* x = (const float*)d_in[0];
  const int* gli = (const int*)d_in[1];
  const void* drop = d_in[2];
  const int* imap = (const int*)d_in[3];
  const void* inr = d_in[4];
  const float* icoord = (const float*)d_in[5];
  const float* gcoord = (const float*)d_in[6];
  const float* W_in = (const float*)d_in[7];
  const float* b_in = (const float*)d_in[8];
  const float* W_pe = (const float*)d_in[9];
  const float* W_bias = (const float*)d_in[10];
  const float* W_v = (const float*)d_in[11];
  const float* W_o = (const float*)d_in[12];
  const float* W1 = (const float*)d_in[13];
  const float* W2 = (const float*)d_in[14];
  const float* g1 = (const float*)d_in[15];
  const float* b1 = (const float*)d_in[16];
  const float* g2 = (const float*)d_in[17];
  const float* b2 = (const float*)d_in[18];
  float* out = (float*)d_out;

  if (ws_size >= (size_t)WS_MASKS_END) {
    const int userows = (ws_size >= (size_t)WS_ROWS_END) ? 1 : 0;
    short* ws = (short*)d_ws;
    char* wsb = (char*)d_ws;
    k_pack<<<dim3(901), dim3(256), 0, stream>>>(
        W_o, W1, W2, W_v, W_in, W_bias, drop, inr, ws);
    k_attn_mfma<<<dim3(B_ * NQ_), dim3(256), 0, stream>>>(
        x, gli, (const unsigned char*)(wsb + DRP8_B),
        (const unsigned char*)(wsb + INR8_B), imap, icoord, gcoord, W_pe, b_in,
        ws + WIP_OFF, ws + WBP_OFF, ws + WVP_OFF,
        (unsigned short*)(wsb + ROWS_B), out, userows);
    k_tail_mfma<<<dim3((B_ * N_) / 32), dim3(256), 0, stream>>>(
        g1, b1, g2, b2, ws + WOP_OFF, ws + W1P_OFF, ws + W2P_OFF,
        (const unsigned short*)(wsb + ROWS_B), out, userows);
  } else if (ws_size >= (size_t)WS_TAIL) {
    short* ws = (short*)d_ws;
    k_pack<<<dim3(325), dim3(256), 0, stream>>>(
        W_o, W1, W2, W_v, W_in, W_bias, drop, inr, ws);
    k_attn_valu<<<dim3(B_ * NQ_), dim3(256), 0, stream>>>(
        x, gli, drop, imap, inr, icoord, gcoord, W_in, b_in, W_pe, W_bias, W_v, out);
    k_tail_mfma<<<dim3((B_ * N_) / 32), dim3(256), 0, stream>>>(
        g1, b1, g2, b2, ws + WOP_OFF, ws + W1P_OFF, ws + W2P_OFF,
        (const unsigned short*)0, out, 0);
  } else {
    k_attn_valu<<<dim3(B_ * NQ_), dim3(256), 0, stream>>>(
        x, gli, drop, imap, inr, icoord, gcoord, W_in, b_in, W_pe, W_bias, W_v, out);
    k_tail<<<dim3((B_ * N_) / 16), dim3(256), 0, stream>>>(
        W_o, W1, W2, g1, b1, g2, b2, out);
  }
}

// Round 16
// 111.923 us; speedup vs baseline: 1.0322x; 1.0322x over previous
//
#include <hip/hip_runtime.h>

#define B_   4
#define N_   4096
#define NH_  16
#define F_   8
#define D_   256
#define FF_  1024
#define H_   8
#define PE_  32
#define NG_  8192
#define NI_  65536
#define NQ_  1024

typedef short short8 __attribute__((ext_vector_type(8)));
typedef float f32x4 __attribute__((ext_vector_type(4)));

union U8 { short8 s8; uint4 u4; };

__device__ __forceinline__ float silu_f(float v) {
  return v * __builtin_amdgcn_rcpf(1.f + __expf(-v));
}
__device__ __forceinline__ unsigned short f2bf(float f) {
  unsigned int x = __float_as_uint(f);
  unsigned int r = (x + 0x7fffu + ((x >> 16) & 1u)) >> 16;
  return (unsigned short)r;
}
__device__ __forceinline__ unsigned int cvt_pk(float a, float b) {
  unsigned int r;
  asm("v_cvt_pk_bf16_f32 %0, %1, %2" : "=v"(r) : "v"(a), "v"(b));
  return r;
}
__device__ __forceinline__ unsigned short f2bf1(float v) {
  return (unsigned short)cvt_pk(v, v);
}
__device__ __forceinline__ float bf2f(unsigned short h) {
  return __uint_as_float(((unsigned int)h) << 16);
}

__device__ __forceinline__ int detect_layout(const unsigned int* w) {
  unsigned b1 = 0, b0 = 0;
#pragma unroll
  for (int i = 0; i < 64; ++i) {
    unsigned v = w[i];
    b1 |= v & 0x0000FF00u;
    b0 |= v & 0x000000FFu;
  }
  return b1 ? 0 : (b0 ? 1 : 2);
}
__device__ __forceinline__ int read_bool(const void* p, int i, int lay) {
  if (lay == 0) return ((const unsigned char*)p)[i] != 0;
  if (lay == 1) return ((const int*)p)[i] != 0;
  return ((const float*)p)[i] != 0.0f;
}

// ---------------------------------------------------------------------------
// Workspace layout.
// ---------------------------------------------------------------------------
#define WOP_OFF 0
#define W1P_OFF 65536
#define W2P_OFF (65536 + 262144)
#define WVP_OFF (65536 + 262144 + 262144)
#define WIP_OFF (65536 + 262144 + 262144 + 65536)
#define WBP_OFF (WIP_OFF + 8192)
#define WS_BASE_B ((WBP_OFF + 512) * 2)
#define DRP8_B  WS_BASE_B
#define INR8_B  (WS_BASE_B + 16384)
#define WS_MASKS_END (INR8_B + 131072)
#define ROWS_B  WS_MASKS_END
#define WS_ROWS_END (ROWS_B + 16384 * 256 * 2)
#define WS_TAIL ((65536 + 262144 + 262144) * 2)

__global__ __launch_bounds__(256) void k_pack(
    const float* __restrict__ Wo, const float* __restrict__ W1,
    const float* __restrict__ W2, const float* __restrict__ Wv,
    const float* __restrict__ Wi, const float* __restrict__ Wb,
    const void* __restrict__ drop, const void* __restrict__ inr,
    short* __restrict__ ws)
{
  int t = blockIdx.x * 256 + threadIdx.x;
  if (t < 8192) {
    int g = t & 3, n = (t >> 2) & 255, kk = t >> 10;
    int k0 = kk * 32 + g * 8;
    short8 v;
#pragma unroll
    for (int j = 0; j < 8; ++j) v[j] = (short)f2bf(Wo[(k0 + j) * 256 + n]);
    *(short8*)(ws + WOP_OFF + t * 8) = v;
  } else if (t < 40960) {
    int u = t - 8192;
    int g = u & 3, n = (u >> 2) & 1023, kk = u >> 12;
    int k0 = kk * 32 + g * 8;
    short8 v;
#pragma unroll
    for (int j = 0; j < 8; ++j) v[j] = (short)f2bf(W1[(k0 + j) * 1024 + n]);
    *(short8*)(ws + W1P_OFF + u * 8) = v;
  } else if (t < 73728) {
    int u = t - 40960;
    int g = u & 3, n = (u >> 2) & 255, kk = u >> 10;
    int k0 = kk * 32 + g * 8;
    short8 v;
#pragma unroll
    for (int j = 0; j < 8; ++j) v[j] = (short)f2bf(W2[(k0 + j) * 256 + n]);
    *(short8*)(ws + W2P_OFF + u * 8) = v;
  } else if (t < 81920) {
    int u = t - 73728;
    int g = u & 3, n = (u >> 2) & 255, kk = u >> 10;
    int k0 = kk * 32 + g * 8;
    short8 v;
#pragma unroll
    for (int j = 0; j < 8; ++j) v[j] = (short)f2bf(Wv[(k0 + j) * 256 + n]);
    *(short8*)(ws + WVP_OFF + u * 8) = v;
  } else if (t < 82944) {
    int u = t - 81920;
    int g = u & 3, n = u >> 2;
    short8 v;
#pragma unroll
    for (int j = 0; j < 8; ++j) {
      int k = g * 8 + j;
      v[j] = (k < 8) ? (short)f2bf(Wi[k * 256 + n]) : (short)0;
    }
    *(short8*)(ws + WIP_OFF + (n * 4 + g) * 8) = v;
  } else if (t < 83008) {
    int u = t - 82944;
    int g = u & 3, col = u >> 2;
    short8 v;
#pragma unroll
    for (int j = 0; j < 8; ++j) {
      int p = g * 8 + j;
      v[j] = (col < 8) ? (short)f2bf(Wb[p * 8 + col]) : (short)0;
    }
    *(short8*)(ws + WBP_OFF + (col * 4 + g) * 8) = v;
  } else if (t >= 83200) {
    int lay = detect_layout((const unsigned int*)inr);
    int t2 = t - 83200;
    char* wsb = (char*)ws;
    if (t2 < B_ * N_) {
      ((unsigned char*)(wsb + DRP8_B))[t2] =
          (unsigned char)read_bool(drop, t2, lay);
    } else if (t2 < B_ * N_ + NG_ * NH_) {
      int u = t2 - B_ * N_;
      ((unsigned char*)(wsb + INR8_B))[u] =
          (unsigned char)read_bool(inr, u, lay);
    }
  }
}

// ---------------------------------------------------------------------------
// MFMA attention kernel v5 (final best-known). 4 waves, 39712 B LDS.
// ---------------------------------------------------------------------------
#define OFF_ATTB  32768
#define OFF_DIST  36864
#define OFF_ANG   37888
#define OFF_KLON  38912
#define OFF_KLAT  39168
#define OFF_KMSK  39424
#define OFF_GLON  39680
#define OFF_GLAT  39696

__global__ __launch_bounds__(256) void k_attn_mfma(
    const float* __restrict__ x, const int* __restrict__ gli,
    const unsigned char* __restrict__ drp8, const unsigned char* __restrict__ inr8,
    const int* __restrict__ imap, const float* __restrict__ icoord,
    const float* __restrict__ gcoord, const float* __restrict__ W_pe,
    const float* __restrict__ b_in, const short* __restrict__ WiP,
    const short* __restrict__ WbP, const short* __restrict__ WvP,
    unsigned short* __restrict__ rows, float* __restrict__ out, int userows)
{
  __shared__ __align__(16) char sm[39712];
  float* distl = (float*)(sm + OFF_DIST);
  float* angl = (float*)(sm + OFF_ANG);
  float* klon = (float*)(sm + OFF_KLON);
  float* klat = (float*)(sm + OFF_KLAT);
  int* kmask = (int*)(sm + OFF_KMSK);
  float* glon = (float*)(sm + OFF_GLON);
  float* glat = (float*)(sm + OFF_GLAT);

  const int grp = blockIdx.x;
  const int b = grp >> 10;
  const int q = grp & (NQ_ - 1);
  const int tid = threadIdx.x;
  const int w = tid >> 6;
  const int l15 = tid & 15;
  const int g = (tid & 63) >> 4;
  const int swz = (l15 & 7) << 4;

  if (tid < 64) {
    int s = tid >> 4;
    int gg = gli[b * N_ + q * 4 + s];
    if ((tid & 15) == 0) {
      glon[s] = gcoord[gg];
      glat[s] = gcoord[NG_ + gg];
    }
    int id = imap[gg * NH_ + (tid & 15)];
    klon[tid] = icoord[id];
    klat[tid] = icoord[NI_ + id];
    kmask[tid] = (inr8[gg * NH_ + (tid & 15)] == 0) |
                 (drp8[b * N_ + q * 4 + s] != 0);
  }

  // ---- MLP via MFMA: xs[64,256] = silu(x @ W_in + b_in) -> xs_T swizzled ----
  {
    short8 a = {0, 0, 0, 0, 0, 0, 0, 0};
    if (g == 0) {
      const float4* xp = (const float4*)(x + (size_t)(b * N_ + q * 4) * 128);
      float4 xa = xp[(w * 16 + l15) * 2];
      float4 xc = xp[(w * 16 + l15) * 2 + 1];
      U8 u;
      u.u4.x = cvt_pk(xa.x, xa.y);
      u.u4.y = cvt_pk(xa.z, xa.w);
      u.u4.z = cvt_pk(xc.x, xc.y);
      u.u4.w = cvt_pk(xc.z, xc.w);
      a = u.s8;
    }
    const int k0 = w * 16 + g * 4;
#pragma unroll
    for (int nf = 0; nf < 16; ++nf) {
      short8 bv = *(const short8*)(WiP + ((nf * 16 + l15) * 4 + g) * 8);
      f32x4 accM = {0.f, 0.f, 0.f, 0.f};
      accM = __builtin_amdgcn_mfma_f32_16x16x32_bf16(a, bv, accM, 0, 0, 0);
      int d = nf * 16 + l15;
      float bn = b_in[d];
      uint2 pv;
      pv.x = cvt_pk(silu_f(accM[0] + bn), silu_f(accM[1] + bn));
      pv.y = cvt_pk(silu_f(accM[2] + bn), silu_f(accM[3] + bn));
      *(uint2*)(sm + ((d * 128 + k0 * 2) ^ ((d & 7) << 4))) = pv;
    }
  }
  __syncthreads();

  // ---- dist/ang per (t,k): row = tid ----
  {
    const int t = tid >> 6, k = tid & 63;
    float dlon = klon[k] - glon[t];
    float dlat = klat[k] - glat[t];
    distl[tid] = sqrtf(dlon * dlon + dlat * dlat + 1e-12f);
    angl[tid] = atan2f(dlat, dlon);
  }
  __syncthreads();

  // ---- scores via MFMA + in-register softmax -> att_bf ----
  {
    float wpe0[8], wpe1[8];
    {
      const float4* wp = (const float4*)W_pe;
      float4 w0a = wp[g * 2], w0b = wp[g * 2 + 1];
      float4 w1a = wp[8 + g * 2], w1b = wp[8 + g * 2 + 1];
      wpe0[0] = w0a.x; wpe0[1] = w0a.y; wpe0[2] = w0a.z; wpe0[3] = w0a.w;
      wpe0[4] = w0b.x; wpe0[5] = w0b.y; wpe0[6] = w0b.z; wpe0[7] = w0b.w;
      wpe1[0] = w1a.x; wpe1[1] = w1a.y; wpe1[2] = w1a.z; wpe1[3] = w1a.w;
      wpe1[4] = w1b.x; wpe1[5] = w1b.y; wpe1[6] = w1b.z; wpe1[7] = w1b.w;
    }
    short8 wb = *(const short8*)(WbP + (l15 * 4 + g) * 8);
    f32x4 accS[4];
#pragma unroll
    for (int i = 0; i < 4; ++i) {
      int row = (w * 4 + i) * 16 + l15;
      float dd = distl[row];
      float aa = angl[row];
      float pe[8];
#pragma unroll
      for (int j = 0; j < 8; ++j)
        pe[j] = silu_f(fmaf(dd, wpe0[j], aa * wpe1[j]));
      U8 pu;
      pu.u4.x = cvt_pk(pe[0], pe[1]);
      pu.u4.y = cvt_pk(pe[2], pe[3]);
      pu.u4.z = cvt_pk(pe[4], pe[5]);
      pu.u4.w = cvt_pk(pe[6], pe[7]);
      f32x4 z = {0.f, 0.f, 0.f, 0.f};
      accS[i] = __builtin_amdgcn_mfma_f32_16x16x32_bf16(pu.s8, wb, z, 0, 0, 0);
    }
    float sv[16];
    float mx = -1e30f;
#pragma unroll
    for (int i = 0; i < 4; ++i)
#pragma unroll
      for (int r = 0; r < 4; ++r) {
        int k = i * 16 + g * 4 + r;
        float s = kmask[k] ? -1e9f : accS[i][r];
        sv[i * 4 + r] = s;
        mx = fmaxf(mx, s);
      }
    mx = fmaxf(mx, __shfl_xor(mx, 16));
    mx = fmaxf(mx, __shfl_xor(mx, 32));
    float sum = 0.f;
#pragma unroll
    for (int u = 0; u < 16; ++u) { sv[u] = __expf(sv[u] - mx); sum += sv[u]; }
    sum += __shfl_xor(sum, 16);
    sum += __shfl_xor(sum, 32);
    float inv = __builtin_amdgcn_rcpf(sum);
    if (l15 < 8) {
      int row = l15 * 4 + w;
      int rs = (row & 7) << 4;
#pragma unroll
      for (int i = 0; i < 4; ++i) {
        uint2 pv;
        pv.x = cvt_pk(sv[i * 4 + 0] * inv, sv[i * 4 + 1] * inv);
        pv.y = cvt_pk(sv[i * 4 + 2] * inv, sv[i * 4 + 3] * inv);
        *(uint2*)(sm + OFF_ATTB + ((row * 128 + (i * 16 + g * 4) * 2) ^ rs)) = pv;
      }
    }
  }
  __syncthreads();

  // ---- y[32,256] = att @ xs (wave w: cols w*64..w*64+63) ----
  f32x4 accY[2][4];
  {
    f32x4 z = {0.f, 0.f, 0.f, 0.f};
#pragma unroll
    for (int mi = 0; mi < 2; ++mi)
#pragma unroll
      for (int ni = 0; ni < 4; ++ni) accY[mi][ni] = z;
  }
#pragma unroll
  for (int kk = 0; kk < 2; ++kk) {
    short8 a0 = *(const short8*)(sm + OFF_ATTB + ((l15 * 128 + kk * 64 + g * 16) ^ swz));
    short8 a1 = *(const short8*)(sm + OFF_ATTB + (((16 + l15) * 128 + kk * 64 + g * 16) ^ swz));
    short8 bf[4];
#pragma unroll
    for (int ni = 0; ni < 4; ++ni)
      bf[ni] = *(const short8*)(sm +
          (((w * 64 + ni * 16 + l15) * 128 + kk * 64 + g * 16) ^ swz));
#pragma unroll
    for (int ni = 0; ni < 4; ++ni) {
      accY[0][ni] = __builtin_amdgcn_mfma_f32_16x16x32_bf16(a0, bf[ni], accY[0][ni], 0, 0, 0);
      accY[1][ni] = __builtin_amdgcn_mfma_f32_16x16x32_bf16(a1, bf[ni], accY[1][ni], 0, 0, 0);
    }
  }
  __syncthreads();   // xs_T dead; overwrite region with y_bf

  // y -> LDS bf16 [32][256] swizzled (base 0)
#pragma unroll
  for (int mi = 0; mi < 2; ++mi)
#pragma unroll
    for (int ni = 0; ni < 4; ++ni)
#pragma unroll
      for (int r = 0; r < 4; ++r) {
        int row = mi * 16 + g * 4 + r;
        int col = w * 64 + ni * 16 + l15;
        *(unsigned short*)(sm + ((row * 512 + col * 2) ^ ((row & 7) << 4))) =
            f2bf1(accY[mi][ni][r]);
      }
  __syncthreads();

  // ---- out[t,col] = sum_c y[h(col)*4+t][c] * Wv[c][col] ----
  {
    const int mf = w >> 1;
    f32x4 accV[4];
    {
      f32x4 z = {0.f, 0.f, 0.f, 0.f};
#pragma unroll
      for (int ni = 0; ni < 4; ++ni) accV[ni] = z;
    }
#pragma unroll
    for (int kk = 0; kk < 8; ++kk) {
      short8 a = *(const short8*)(sm +
          (((mf * 16 + l15) * 512 + kk * 64 + g * 16) ^ swz));
#pragma unroll
      for (int ni = 0; ni < 4; ++ni) {
        int col = w * 64 + ni * 16 + l15;
        short8 bv = *(const short8*)(WvP + ((size_t)(kk * 256 + col)) * 32 + g * 8);
        accV[ni] = __builtin_amdgcn_mfma_f32_16x16x32_bf16(a, bv, accV[ni], 0, 0, 0);
      }
    }
    float* outl = (float*)(sm + 16384);
    const int gb = (w & 1) * 2;
#pragma unroll
    for (int ni = 0; ni < 4; ++ni) {
      if (g == gb + (ni >> 1)) {
#pragma unroll
        for (int r = 0; r < 4; ++r)
          outl[r * 256 + w * 64 + ni * 16 + l15] = accV[ni][r];
      }
    }
  }
  __syncthreads();

  if (userows) {
    const float* outl = (const float*)(sm + 16384);
    unsigned* rb = (unsigned*)(rows + (size_t)grp * (4 * D_));
    int t2 = tid >> 7;
    int c2 = tid & 127;
#pragma unroll
    for (int tt = 0; tt < 2; ++tt) {
      int t = tt * 2 + t2;
      rb[t * 128 + c2] = cvt_pk(outl[t * 256 + 2 * c2],
                                outl[t * 256 + 2 * c2 + 1]);
    }
  } else {
    const float* outl = (const float*)(sm + 16384);
    float* ob = out + (size_t)grp * (4 * D_);
#pragma unroll
    for (int t = 0; t < 4; ++t) ob[t * 256 + tid] = outl[t * 256 + tid];
  }
}

// ---------------------------------------------------------------------------
// Fallback VALU attention (round-2, passing).
// ---------------------------------------------------------------------------
__global__ __launch_bounds__(256) void k_attn_valu(
    const float* __restrict__ x, const int* __restrict__ gli,
    const void* __restrict__ drop, const int* __restrict__ imap,
    const void* __restrict__ inr, const float* __restrict__ icoord,
    const float* __restrict__ gcoord, const float* __restrict__ W_in,
    const float* __restrict__ b_in, const float* __restrict__ W_pe,
    const float* __restrict__ W_bias, const float* __restrict__ W_v,
    float* __restrict__ out)
{
  __shared__ __align__(16) float xl[512];
  __shared__ float glon[4], glat[4];
  __shared__ int gidx[4], dropf[4];
  __shared__ float klon[64], klat[64];
  __shared__ int kmask[64];
  __shared__ __align__(16) unsigned short xs[64 * D_];
  __shared__ __align__(16) float att[32 * 64];
  __shared__ __align__(16) float yl[4 * 8 * 260];

  const int grp = blockIdx.x;
  const int b = grp >> 10;
  const int q = grp & (NQ_ - 1);
  const int tid = threadIdx.x;
  const int lay = detect_layout((const unsigned int*)inr);

  if (tid < 4) {
    int g = gli[b * N_ + q * 4 + tid];
    gidx[tid] = g;
    glon[tid] = gcoord[g];
    glat[tid] = gcoord[NG_ + g];
    dropf[tid] = read_bool(drop, b * N_ + q * 4 + tid, lay);
  }
  const float* xb = x + (size_t)(b * N_ + q * 4) * (NH_ * F_);
  xl[tid] = xb[tid];
  xl[tid + 256] = xb[tid + 256];
  __syncthreads();

  if (tid < 64) {
    int s = tid >> 4;
    int g = gidx[s];
    int id = imap[g * NH_ + (tid & 15)];
    klon[tid] = icoord[id];
    klat[tid] = icoord[NI_ + id];
    kmask[tid] = (read_bool(inr, g * NH_ + (tid & 15), lay) == 0) | dropf[s];
  }
  {
    float w[8];
#pragma unroll
    for (int c = 0; c < 8; ++c) w[c] = W_in[c * D_ + tid];
    float bi = b_in[tid];
#pragma unroll 4
    for (int k = 0; k < 64; ++k) {
      float v = bi;
#pragma unroll
      for (int c = 0; c < 8; ++c) v = fmaf(xl[k * 8 + c], w[c], v);
      xs[k * D_ + tid] = f2bf(silu_f(v));
    }
  }
  __syncthreads();
  {
    const int t = tid >> 6, k = tid & 63;
    float dlon = klon[k] - glon[t];
    float dlat = klat[k] - glat[t];
    float dist = sqrtf(dlon * dlon + dlat * dlat + 1e-12f);
    float ang = atan2f(dlat, dlon);
    float bias[8];
#pragma unroll
    for (int h = 0; h < 8; ++h) bias[h] = 0.f;
#pragma unroll
    for (int p = 0; p < 32; ++p) {
      float pv = silu_f(fmaf(dist, W_pe[p], ang * W_pe[32 + p]));
#pragma unroll
      for (int h = 0; h < 8; ++h) bias[h] = fmaf(pv, W_bias[p * 8 + h], bias[h]);
    }
    const bool mk = (kmask[k] != 0);
#pragma unroll
    for (int h = 0; h < 8; ++h)
      att[(h * 4 + t) * 64 + k] = mk ? -1e9f : bias[h];
  }
  __syncthreads();
  {
    const int row = tid >> 3, l8 = tid & 7;
    float sv[8];
    float mx = -1e30f;
#pragma unroll
    for (int i = 0; i < 8; ++i) { sv[i] = att[row * 64 + l8 + i * 8]; mx = fmaxf(mx, sv[i]); }
#pragma unroll
    for (int off = 1; off < 8; off <<= 1) mx = fmaxf(mx, __shfl_xor(mx, off, 8));
    float sm = 0.f;
#pragma unroll
    for (int i = 0; i < 8; ++i) { sv[i] = __expf(sv[i] - mx); sm += sv[i]; }
#pragma unroll
    for (int off = 1; off < 8; off <<= 1) sm += __shfl_xor(sm, off, 8);
    float inv = 1.f / sm;
#pragma unroll
    for (int i = 0; i < 8; ++i) att[row * 64 + l8 + i * 8] = sv[i] * inv;
  }
  __syncthreads();
  {
    float acc[32];
#pragma unroll
    for (int r = 0; r < 32; ++r) acc[r] = 0.f;
    for (int k4 = 0; k4 < 64; k4 += 4) {
      float xv0 = bf2f(xs[(k4 + 0) * D_ + tid]);
      float xv1 = bf2f(xs[(k4 + 1) * D_ + tid]);
      float xv2 = bf2f(xs[(k4 + 2) * D_ + tid]);
      float xv3 = bf2f(xs[(k4 + 3) * D_ + tid]);
#pragma unroll
      for (int r = 0; r < 32; ++r) {
        float4 a = *(const float4*)&att[r * 64 + k4];
        acc[r] = fmaf(a.x, xv0, acc[r]);
        acc[r] = fmaf(a.y, xv1, acc[r]);
        acc[r] = fmaf(a.z, xv2, acc[r]);
        acc[r] = fmaf(a.w, xv3, acc[r]);
      }
    }
#pragma unroll
    for (int r = 0; r < 32; ++r)
      yl[(r & 3) * 2080 + (r >> 2) * 260 + tid] = acc[r];
  }
  __syncthreads();
  {
    const int h = tid >> 5;
    float o0 = 0.f, o1 = 0.f, o2 = 0.f, o3 = 0.f;
    for (int c = 0; c < 256; c += 4) {
      float w0 = W_v[(c + 0) * D_ + tid];
      float w1 = W_v[(c + 1) * D_ + tid];
      float w2 = W_v[(c + 2) * D_ + tid];
      float w3 = W_v[(c + 3) * D_ + tid];
      float4 y0 = *(const float4*)&yl[0 * 2080 + h * 260 + c];
      float4 y1 = *(const float4*)&yl[1 * 2080 + h * 260 + c];
      float4 y2 = *(const float4*)&yl[2 * 2080 + h * 260 + c];
      float4 y3 = *(const float4*)&yl[3 * 2080 + h * 260 + c];
      o0 = fmaf(y0.x, w0, o0); o0 = fmaf(y0.y, w1, o0); o0 = fmaf(y0.z, w2, o0); o0 = fmaf(y0.w, w3, o0);
      o1 = fmaf(y1.x, w0, o1); o1 = fmaf(y1.y, w1, o1); o1 = fmaf(y1.z, w2, o1); o1 = fmaf(y1.w, w3, o1);
      o2 = fmaf(y2.x, w0, o2); o2 = fmaf(y2.y, w1, o2); o2 = fmaf(y2.z, w2, o2); o2 = fmaf(y2.w, w3, o2);
      o3 = fmaf(y3.x, w0, o3); o3 = fmaf(y3.y, w1, o3); o3 = fmaf(y3.z, w2, o3); o3 = fmaf(y3.w, w3, o3);
    }
    float* ob = out + (size_t)grp * (4 * D_);
    ob[0 * D_ + tid] = o0;
    ob[1 * D_ + tid] = o1;
    ob[2 * D_ + tid] = o2;
    ob[3 * D_ + tid] = o3;
  }
}

// ---------------------------------------------------------------------------
// MFMA tail: 32 rows/block, 512 blocks; bf16 or f32 source.
// ---------------------------------------------------------------------------
template<int MI>
__device__ __forceinline__ void gemm_mfma(
    f32x4 acc[MI][4], const char* As, const short* Bp,
    int N, int kk0, int colbase, int l15, int g)
{
#pragma unroll
  for (int kk = 0; kk < 8; ++kk) {
    short8 a[MI], bv[4];
#pragma unroll
    for (int mi = 0; mi < MI; ++mi) {
      int row = mi * 16 + l15;
      int byte = (row * 512 + kk * 64 + g * 16) ^ ((row & 7) << 4);
      a[mi] = *(const short8*)(As + byte);
    }
#pragma unroll
    for (int ni = 0; ni < 4; ++ni) {
      int col = colbase + ni * 16 + l15;
      size_t off = ((size_t)(kk0 + kk) * N + col) * 32 + g * 8;
      bv[ni] = *(const short8*)(Bp + off);
    }
#pragma unroll
    for (int mi = 0; mi < MI; ++mi)
#pragma unroll
      for (int ni = 0; ni < 4; ++ni)
        acc[mi][ni] = __builtin_amdgcn_mfma_f32_16x16x32_bf16(
            a[mi], bv[ni], acc[mi][ni], 0, 0, 0);
  }
}

__global__ __launch_bounds__(256) void k_tail_mfma(
    const float* __restrict__ g1v, const float* __restrict__ b1v,
    const float* __restrict__ g2v, const float* __restrict__ b2v,
    const short* __restrict__ WoP, const short* __restrict__ W1P,
    const short* __restrict__ W2P, const unsigned short* __restrict__ rowsrc,
    float* __restrict__ io, int userows)
{
  __shared__ __align__(16) unsigned short sA1[32 * 256];
  __shared__ __align__(16) unsigned short sU[32 * 256];
  __shared__ float sPs[4][32];
  __shared__ float sPss[4][32];

  const int tid = threadIdx.x;
  const int w = tid >> 6;
  const int l15 = tid & 15;
  const int g = (tid & 63) >> 4;
  float* base = io + (size_t)blockIdx.x * (32 * 256);

  if (userows) {
    const unsigned short* rb = rowsrc + (size_t)blockIdx.x * (32 * 256);
#pragma unroll
    for (int i = 0; i < 8; ++i) {
      int e = (tid + 256 * i) * 4;
      int row = e >> 8, c = e & 255;
      uint2 v = *(const uint2*)(rb + e);
      int byte = (row * 512 + c * 2) ^ ((row & 7) << 4);
      *(uint2*)((char*)sU + byte) = v;
    }
  } else {
#pragma unroll
    for (int i = 0; i < 8; ++i) {
      int e = (tid + 256 * i) * 4;
      int row = e >> 8, c = e & 255;
      float4 v = *(const float4*)(base + e);
      uint2 pv;
      pv.x = cvt_pk(v.x, v.y);
      pv.y = cvt_pk(v.z, v.w);
      int byte = (row * 512 + c * 2) ^ ((row & 7) << 4);
      *(uint2*)((char*)sU + byte) = pv;
    }
  }
  __syncthreads();

  f32x4 acc[2][4];
  {
    f32x4 z = {0.f, 0.f, 0.f, 0.f};
#pragma unroll
    for (int mi = 0; mi < 2; ++mi)
#pragma unroll
      for (int ni = 0; ni < 4; ++ni) acc[mi][ni] = z;
  }
  gemm_mfma<2>(acc, (const char*)sU, WoP, 256, 0, w * 64, l15, g);

#pragma unroll
  for (int mi = 0; mi < 2; ++mi)
#pragma unroll
    for (int r = 0; r < 4; ++r) {
      float a0 = acc[mi][0][r], a1 = acc[mi][1][r], a2 = acc[mi][2][r], a3 = acc[mi][3][r];
      float s = a0 + a1 + a2 + a3;
      float ss = a0 * a0 + a1 * a1 + a2 * a2 + a3 * a3;
#pragma unroll
      for (int off = 1; off < 16; off <<= 1) {
        s += __shfl_xor(s, off);
        ss += __shfl_xor(ss, off);
      }
      if (l15 == 0) {
        int row = 16 * mi + 4 * g + r;
        sPs[w][row] = s;
        sPss[w][row] = ss;
      }
    }
  __syncthreads();

  {
    float ga[4], bb[4];
#pragma unroll
    for (int ni = 0; ni < 4; ++ni) {
      int col = 64 * w + 16 * ni + l15;
      ga[ni] = g1v[col];
      bb[ni] = b1v[col];
    }
#pragma unroll
    for (int mi = 0; mi < 2; ++mi)
#pragma unroll
      for (int r = 0; r < 4; ++r) {
        int row = 16 * mi + 4 * g + r;
        float S = sPs[0][row] + sPs[1][row] + sPs[2][row] + sPs[3][row];
        float SS = sPss[0][row] + sPss[1][row] + sPss[2][row] + sPss[3][row];
        float mu = S * (1.f / 256.f);
        float rs = rsqrtf(SS * (1.f / 256.f) - mu * mu + 1e-5f);
#pragma unroll
        for (int ni = 0; ni < 4; ++ni) {
          int col = 64 * w + 16 * ni + l15;
          float val = (acc[mi][ni][r] - mu) * rs * ga[ni] + bb[ni];
          acc[mi][ni][r] = val;
          int byte = (row * 512 + col * 2) ^ ((row & 7) << 4);
          *(unsigned short*)((char*)sA1 + byte) = f2bf1(val);
        }
      }
  }
  __syncthreads();

  for (int p = 0; p < 4; ++p) {
    f32x4 acc2[2][4];
    {
      f32x4 z = {0.f, 0.f, 0.f, 0.f};
#pragma unroll
      for (int mi = 0; mi < 2; ++mi)
#pragma unroll
        for (int ni = 0; ni < 4; ++ni) acc2[mi][ni] = z;
    }
    gemm_mfma<2>(acc2, (const char*)sA1, W1P, 1024, 0, p * 256 + w * 64, l15, g);
#pragma unroll
    for (int mi = 0; mi < 2; ++mi)
#pragma unroll
      for (int ni = 0; ni < 4; ++ni)
#pragma unroll
        for (int r = 0; r < 4; ++r) {
          int row = 16 * mi + 4 * g + r;
          int col = 64 * w + 16 * ni + l15;
          int byte = (row * 512 + col * 2) ^ ((row & 7) << 4);
          *(unsigned short*)((char*)sU + byte) = f2bf1(silu_f(acc2[mi][ni][r]));
        }
    __syncthreads();
    gemm_mfma<2>(acc, (const char*)sU, W2P, 256, p * 8, w * 64, l15, g);
    __syncthreads();
  }

#pragma unroll
  for (int mi = 0; mi < 2; ++mi)
#pragma unroll
    for (int r = 0; r < 4; ++r) {
      float a0 = acc[mi][0][r], a1 = acc[mi][1][r], a2 = acc[mi][2][r], a3 = acc[mi][3][r];
      float s = a0 + a1 + a2 + a3;
      float ss = a0 * a0 + a1 * a1 + a2 * a2 + a3 * a3;
#pragma unroll
      for (int off = 1; off < 16; off <<= 1) {
        s += __shfl_xor(s, off);
        ss += __shfl_xor(ss, off);
      }
      if (l15 == 0) {
        int row = 16 * mi + 4 * g + r;
        sPs[w][row] = s;
        sPss[w][row] = ss;
      }
    }
  __syncthreads();

  {
    float ga[4], bb[4];
#pragma unroll
    for (int ni = 0; ni < 4; ++ni) {
      int col = 64 * w + 16 * ni + l15;
      ga[ni] = g2v[col];
      bb[ni] = b2v[col];
    }
#pragma unroll
    for (int mi = 0; mi < 2; ++mi)
#pragma unroll
      for (int r = 0; r < 4; ++r) {
        int row = 16 * mi + 4 * g + r;
        float S = sPs[0][row] + sPs[1][row] + sPs[2][row] + sPs[3][row];
        float SS = sPss[0][row] + sPss[1][row] + sPss[2][row] + sPss[3][row];
        float mu = S * (1.f / 256.f);
        float rs = rsqrtf(SS * (1.f / 256.f) - mu * mu + 1e-5f);
#pragma unroll
        for (int ni = 0; ni < 4; ++ni) {
          int col = 64 * w + 16 * ni + l15;
          base[row * 256 + col] = (acc[mi][ni][r] - mu) * rs * ga[ni] + bb[ni];
        }
      }
  }
}

// ---------------------------------------------------------------------------
// Fallback VALU tail.
// ---------------------------------------------------------------------------
__global__ __launch_bounds__(256) void k_tail(
    const float* __restrict__ Wo, const float* __restrict__ W1,
    const float* __restrict__ W2, const float* __restrict__ g1,
    const float* __restrict__ b1, const float* __restrict__ g2,
    const float* __restrict__ b2, float* __restrict__ io)
{
  __shared__ __align__(16) float rl[16 * 260];
  __shared__ __align__(16) float h1[16 * 260];
  __shared__ __align__(16) unsigned short u[16 * FF_];
  const int tid = threadIdx.x;
  float* base = io + (size_t)blockIdx.x * (16 * D_);

#pragma unroll
  for (int r = 0; r < 16; ++r) rl[r * 260 + tid] = base[r * D_ + tid];
  __syncthreads();
  {
    float acc[16];
#pragma unroll
    for (int r = 0; r < 16; ++r) acc[r] = 0.f;
    for (int c = 0; c < 256; c += 4) {
      float w0 = Wo[(c + 0) * D_ + tid], w1 = Wo[(c + 1) * D_ + tid];
      float w2 = Wo[(c + 2) * D_ + tid], w3 = Wo[(c + 3) * D_ + tid];
#pragma unroll
      for (int r = 0; r < 16; ++r) {
        float4 rv = *(const float4*)&rl[r * 260 + c];
        acc[r] = fmaf(rv.x, w0, acc[r]); acc[r] = fmaf(rv.y, w1, acc[r]);
        acc[r] = fmaf(rv.z, w2, acc[r]); acc[r] = fmaf(rv.w, w3, acc[r]);
      }
    }
#pragma unroll
    for (int r = 0; r < 16; ++r) h1[r * 260 + tid] = acc[r];
  }
  __syncthreads();
  {
    const int r = tid >> 4, l = tid & 15;
    float s = 0.f, ss = 0.f;
#pragma unroll
    for (int i = 0; i < 16; ++i) { float v = h1[r * 260 + l + i * 16]; s += v; ss += v * v; }
#pragma unroll
    for (int off = 1; off < 16; off <<= 1) { s += __shfl_xor(s, off, 16); ss += __shfl_xor(ss, off, 16); }
    float mu = s * (1.f / 256.f);
    float rs = rsqrtf(ss * (1.f / 256.f) - mu * mu + 1e-5f);
#pragma unroll
    for (int i = 0; i < 16; ++i) {
      int d = l + i * 16;
      h1[r * 260 + d] = (h1[r * 260 + d] - mu) * rs * g1[d] + b1[d];
    }
  }
  __syncthreads();
  for (int fo = 0; fo < 4; ++fo) {
    const int f = fo * 256 + tid;
    float a2[16];
#pragma unroll
    for (int r = 0; r < 16; ++r) a2[r] = 0.f;
    for (int c = 0; c < 256; c += 4) {
      float w0 = W1[(c + 0) * FF_ + f], w1 = W1[(c + 1) * FF_ + f];
      float w2 = W1[(c + 2) * FF_ + f], w3 = W1[(c + 3) * FF_ + f];
#pragma unroll
      for (int r = 0; r < 16; ++r) {
        float4 hv = *(const float4*)&h1[r * 260 + c];
        a2[r] = fmaf(hv.x, w0, a2[r]); a2[r] = fmaf(hv.y, w1, a2[r]);
        a2[r] = fmaf(hv.z, w2, a2[r]); a2[r] = fmaf(hv.w, w3, a2[r]);
      }
    }
#pragma unroll
    for (int r = 0; r < 16; ++r) u[r * FF_ + f] = f2bf(silu_f(a2[r]));
  }
  __syncthreads();
  {
    float a3[16];
#pragma unroll
    for (int r = 0; r < 16; ++r) a3[r] = h1[r * 260 + tid];
    for (int f = 0; f < FF_; f += 8) {
      float w[8];
#pragma unroll
      for (int i = 0; i < 8; ++i) w[i] = W2[(f + i) * D_ + tid];
#pragma unroll
      for (int r = 0; r < 16; ++r) {
        uint4 uv = *(const uint4*)&u[r * FF_ + f];
        a3[r] = fmaf(__uint_as_float(uv.x << 16), w[0], a3[r]);
        a3[r] = fmaf(__uint_as_float(uv.x & 0xffff0000u), w[1], a3[r]);
        a3[r] = fmaf(__uint_as_float(uv.y << 16), w[2], a3[r]);
        a3[r] = fmaf(__uint_as_float(uv.y & 0xffff0000u), w[3], a3[r]);
        a3[r] = fmaf(__uint_as_float(uv.z << 16), w[4], a3[r]);
        a3[r] = fmaf(__uint_as_float(uv.z & 0xffff0000u), w[5], a3[r]);
        a3[r] = fmaf(__uint_as_float(uv.w << 16), w[6], a3[r]);
        a3[r] = fmaf(__uint_as_float(uv.w & 0xffff0000u), w[7], a3[r]);
      }
    }
#pragma unroll
    for (int r = 0; r < 16; ++r) rl[r * 260 + tid] = a3[r];
  }
  __syncthreads();
  {
    const int r = tid >> 4, l = tid & 15;
    float s = 0.f, ss = 0.f;
#pragma unroll
    for (int i = 0; i < 16; ++i) { float v = rl[r * 260 + l + i * 16]; s += v; ss += v * v; }
#pragma unroll
    for (int off = 1; off < 16; off <<= 1) { s += __shfl_xor(s, off, 16); ss += __shfl_xor(ss, off, 16); }
    float mu = s * (1.f / 256.f);
    float rs = rsqrtf(ss * (1.f / 256.f) - mu * mu + 1e-5f);
#pragma unroll
    for (int i = 0; i < 16; ++i) {
      int d = l + i * 16;
      base[r * D_ + d] = (rl[r * 260 + d] - mu) * rs * g2[d] + b2[d];
    }
  }
}

extern "C" void kernel_launch(void* const* d_in, const int* in_sizes, int n_in,
                              void* d_out, int out_size, void* d_ws, size_t ws_size,
                              hipStream_t stream) {
  (void)in_sizes; (void)n_in; (void)out_size;
  const float* x = (const float*)d_in[0];
  const int* gli = (const int*)d_in[1];
  const void* drop = d_in[2];
  const int* imap = (const int*)d_in[3];
  const void* inr = d_in[4];
  const float* icoord = (const float*)d_in[5];
  const float* gcoord = (const float*)d_in[6];
  const float* W_in = (const float*)d_in[7];
  const float* b_in = (const float*)d_in[8];
  const float* W_pe = (const float*)d_in[9];
  const float* W_bias = (const float*)d_in[10];
  const float* W_v = (const float*)d_in[11];
  const float* W_o = (const float*)d_in[12];
  const float* W1 = (const float*)d_in[13];
  const float* W2 = (const float*)d_in[14];
  const float* g1 = (const float*)d_in[15];
  const float* b1 = (const float*)d_in[16];
  const float* g2 = (const float*)d_in[17];
  const float* b2 = (const float*)d_in[18];
  float* out = (float*)d_out;

  if (ws_size >= (size_t)WS_MASKS_END) {
    const int userows = (ws_size >= (size_t)WS_ROWS_END) ? 1 : 0;
    short* ws = (short*)d_ws;
    char* wsb = (char*)d_ws;
    k_pack<<<dim3(901), dim3(256), 0, stream>>>(
        W_o, W1, W2, W_v, W_in, W_bias, drop, inr, ws);
    k_attn_mfma<<<dim3(B_ * NQ_), dim3(256), 0, stream>>>(
        x, gli, (const unsigned char*)(wsb + DRP8_B),
        (const unsigned char*)(wsb + INR8_B), imap, icoord, gcoord, W_pe, b_in,
        ws + WIP_OFF, ws + WBP_OFF, ws + WVP_OFF,
        (unsigned short*)(wsb + ROWS_B), out, userows);
    k_tail_mfma<<<dim3((B_ * N_) / 32), dim3(256), 0, stream>>>(
        g1, b1, g2, b2, ws + WOP_OFF, ws + W1P_OFF, ws + W2P_OFF,
        (const unsigned short*)(wsb + ROWS_B), out, userows);
  } else if (ws_size >= (size_t)WS_TAIL) {
    short* ws = (short*)d_ws;
    k_pack<<<dim3(325), dim3(256), 0, stream>>>(
        W_o, W1, W2, W_v, W_in, W_bias, drop, inr, ws);
    k_attn_valu<<<dim3(B_ * NQ_), dim3(256), 0, stream>>>(
        x, gli, drop, imap, inr, icoord, gcoord, W_in, b_in, W_pe, W_bias, W_v, out);
    k_tail_mfma<<<dim3((B_ * N_) / 32), dim3(256), 0, stream>>>(
        g1, b1, g2, b2, ws + WOP_OFF, ws + W1P_OFF, ws + W2P_OFF,
        (const unsigned short*)0, out, 0);
  } else {
    k_attn_valu<<<dim3(B_ * NQ_), dim3(256), 0, stream>>>(
        x, gli, drop, imap, inr, icoord, gcoord, W_in, b_in, W_pe, W_bias, W_v, out);
    k_tail<<<dim3((B_ * N_) / 16), dim3(256), 0, stream>>>(
        W_o, W1, W2, g1, b1, g2, b2, out);
  }
}